// Round 1
// 399.498 us; speedup vs baseline: 1.1086x; 1.1086x over previous
//
#include <hip/hip_runtime.h>
#include <stdint.h>

#define NW 741
#define NEG_INF_KEY 0x007FFFFFu  // key(-inf); real finite scores map strictly above

typedef float f2 __attribute__((ext_vector_type(2)));

__device__ __forceinline__ unsigned score_key(float f) {
  const unsigned u = __float_as_uint(f);
  return (u & 0x80000000u) ? ~u : (u | 0x80000000u);
}
__device__ __forceinline__ float key_score(unsigned k) {
  return __uint_as_float((k & 0x80000000u) ? (k ^ 0x80000000u) : ~k);
}

// 6-step DPP argmax over the 64-lane wave (tie -> lowest index), result
// broadcast via readlane. VALU-only: keeps the LDS pipe free.
template<int CTRL>
__device__ __forceinline__ void argmax_step(unsigned& k, int& i) {
  const unsigned tk = (unsigned)__builtin_amdgcn_update_dpp(0, (int)k, CTRL, 0xF, 0xF, true);
  const int ti = __builtin_amdgcn_update_dpp(0, i, CTRL, 0xF, 0xF, true);
  if (tk > k || (tk == k && ti < i)) { k = tk; i = ti; }
}
__device__ __forceinline__ void wave_argmax(unsigned& k, int& i) {
  argmax_step<0x111>(k, i);  // row_shr:1
  argmax_step<0x112>(k, i);  // row_shr:2
  argmax_step<0x114>(k, i);  // row_shr:4
  argmax_step<0x118>(k, i);  // row_shr:8
  argmax_step<0x142>(k, i);  // row_bcast15
  argmax_step<0x143>(k, i);  // row_bcast31
  k = (unsigned)__builtin_amdgcn_readlane((int)k, 63);
  i = __builtin_amdgcn_readlane(i, 63);
}

// Bit-exact chained row-major fp32 window sum for TWO images at once.
// im2[k] = {imgA[k], imgB[k]}; per-component adds are independent IEEE fp32
// chains identical to the reference order (v_pk_add_f32 or 2x v_add_f32).
// Keys go to REGISTER slots kA/kB[SB..SB+NS) (no LDS).
// Bank-conflict fix: 4 copies of the image pair at +392-dword (== +8 bank)
// offsets; window o uses copy (o/P)&3 with P = Wo+2, which is exactly the
// lane distance of the (di+1, dj+2) same-bank chain -> chains split across
// copies -> only free 2-way aliasing remains.
template<int H, int W, int OFF, int NS, int SB>
__device__ __forceinline__ void score_ratio2(const f2* __restrict__ im2,
                                             unsigned* __restrict__ kA,
                                             unsigned* __restrict__ kB,
                                             float* __restrict__ wrowA,
                                             float* __restrict__ wrowB,
                                             const int lane, const bool hasB) {
  constexpr int Wo = 14 - W + 1;
  constexpr int Ho = 14 - H + 1;
  constexpr int NWIN = Ho * Wo;
  constexpr int P = Wo + 2;  // same-bank chain period for this ratio
#pragma unroll
  for (int s = 0; s < NS; ++s) {
    const int o = lane + 64 * s;
    unsigned ka = 0u, kb = 0u;
    if (o < NWIN) {
      const int i = o / Wo, j = o - i * Wo;
      const int cp = (o / P) & 3;           // bank-rotation copy select
      const f2* p = im2 + cp * 196 + (i * 14 + j);
      f2 acc = {0.0f, 0.0f};
#pragma unroll
      for (int di = 0; di < H; ++di)
#pragma unroll
        for (int dj = 0; dj < W; ++dj)
          acc += p[di * 14 + dj];           // ds_read_b64, chained adds
      const float scA = acc.x / (float)(H * W);   // IEEE fp32 div (as before)
      const float scB = acc.y / (float)(H * W);
      wrowA[OFF + o] = scA;
      if (hasB) wrowB[OFF + o] = scB;
      ka = score_key(scA);
      kb = score_key(scB);
    }
    kA[SB + s] = ka;   // constant index after unroll -> stays in VGPRs
    kB[SB + s] = kb;
  }
}

__global__ __launch_bounds__(256, 4) void appm_kernel(
    const float* __restrict__ x, const int* __restrict__ coords,
    float* __restrict__ out, int B) {

  __shared__ float4 c_box[NW];
  __shared__ float c_ar[NW];
  __shared__ f2 imgp[4][784];   // per wave: 4 bank-rotated copies of 196 x {imgA,imgB}
  // LDS total: 11856 + 2964 + 25088 = 39908 B -> 4 blocks/CU (16 waves)

  const int t = threadIdx.x;
  const int wv = t >> 6;
  const int lane = t & 63;
  const int img0 = blockIdx.x * 8;
  const int imgA = img0 + wv * 2;
  const int imgB = imgA + 1;
  const bool hasA = (imgA < B);
  const bool hasB = (imgB < B);

  // ---- Phase A: coord tables (float4 box + area), shared per block ----
  for (int w = t; w < NW; w += 256) {
    const int4 c = ((const int4*)coords)[w];
    const float fx0 = (float)c.x, fy0 = (float)c.y;
    const float fx1 = (float)c.z, fy1 = (float)c.w;
    c_box[w] = make_float4(fx0, fy0, fx1, fy1);
    c_ar[w] = (fx1 - fx0 + 1.0f) * (fy1 - fy0 + 1.0f);
  }

  // ---- Phase B: stage 8 images, pair-interleaved, 4 copies per wave ----
  {
    int nimg = B - img0; if (nimg > 8) nimg = 8;
    const int lim = nimg * 196;
    const float* xb = x + (long long)img0 * 196;
    for (int u = t; u < lim; u += 256) {
      const int i = u / 196, k = u - i * 196;
      const float v = xb[u];
      float* dst = (float*)imgp[i >> 1];
      const int fi = k * 2 + (i & 1);
#pragma unroll
      for (int cp = 0; cp < 4; ++cp)
        dst[cp * 392 + fi] = v;   // 2-way write aliasing only (free)
    }
  }
  __syncthreads();

  if (hasA) {
    const f2* im2 = imgp[wv];
    float* wrowA = out + (long long)B * 12 + (long long)imgA * NW;
    float* wrowB = wrowA + NW;

    // Register key slots: {ratio,slot} -> global slot id. 15 per image.
    unsigned kA[15], kB[15];

    // ---- Phase C: 741 window scores for both images ----
    score_ratio2<4, 4, 0, 2, 0>(im2, kA, kB, wrowA, wrowB, lane, hasB);
    score_ratio2<3, 5, 121, 2, 2>(im2, kA, kB, wrowA, wrowB, lane, hasB);
    score_ratio2<5, 3, 241, 2, 4>(im2, kA, kB, wrowA, wrowB, lane, hasB);
    score_ratio2<6, 6, 361, 2, 6>(im2, kA, kB, wrowA, wrowB, lane, hasB);
    score_ratio2<5, 7, 442, 2, 8>(im2, kA, kB, wrowA, wrowB, lane, hasB);
    score_ratio2<7, 5, 522, 2, 10>(im2, kA, kB, wrowA, wrowB, lane, hasB);
    score_ratio2<8, 8, 602, 1, 12>(im2, kA, kB, wrowA, wrowB, lane, hasB);
    score_ratio2<6, 10, 651, 1, 13>(im2, kA, kB, wrowA, wrowB, lane, hasB);
    score_ratio2<10, 6, 696, 1, 14>(im2, kA, kB, wrowA, wrowB, lane, hasB);

    // ---- Phase D: greedy NMS for both images, 3 groups, keys in VGPRs ----
    // Global window index of slot s at this lane = SBASE[s] + lane.
    // Inactive lanes hold key 0, so no extra masking is needed.
    constexpr int SBASE[15] = {0, 64, 121, 185, 241, 305, 361, 425,
                               442, 506, 522, 586, 602, 651, 696};
    constexpr int GS[3] = {0, 6, 12};
    constexpr int GE[3] = {6, 12, 15};
    constexpr int GN[3] = {3, 2, 1};
    constexpr int GW0[3] = {0, 361, 602};   // group start window index

    float myIA = 0.0f, mySA = 0.0f, myIB = 0.0f, mySB = 0.0f;
    int pick = 0;
#pragma unroll
    for (int g = 0; g < 3; ++g) {
      int lastA = GW0[g], lastB = GW0[g];
      float lastSA = 0.0f, lastSB = 0.0f;
#pragma unroll
      for (int n = 0; n < GN[g]; ++n) {
        unsigned bkA = 0u, bkB = 0u;
        int biA = 0, biB = 0;
#pragma unroll
        for (int s = GS[g]; s < GE[g]; ++s) {   // register scan (no LDS)
          const int o = SBASE[s] + lane;
          if (kA[s] > bkA) { bkA = kA[s]; biA = o; }
          if (kB[s] > bkB) { bkB = kB[s]; biB = o; }
        }
        wave_argmax(bkA, biA);
        wave_argmax(bkB, biB);

        int idxA, idxB; float scA, scB;
        if (bkA > NEG_INF_KEY) { idxA = biA; scA = key_score(bkA); }
        else { idxA = lastA; scA = lastSA; }
        if (bkB > NEG_INF_KEY) { idxB = biB; scB = key_score(bkB); }
        else { idxB = lastB; scB = lastSB; }
        lastA = idxA; lastSA = scA;
        lastB = idxB; lastSB = scB;
        if (lane == pick) { myIA = (float)idxA; mySA = scA; myIB = (float)idxB; mySB = scB; }
        pick++;

        if (n + 1 < GN[g]) {
          // suppression: exact compare 4*inter > union  <=>  iou > 0.25
          const float4 bA = c_box[idxA]; const float aA = c_ar[idxA];  // broadcast
          const float4 bB = c_box[idxB]; const float aB = c_ar[idxB];
#pragma unroll
          for (int s = GS[g]; s < GE[g]; ++s) {
            const int o = SBASE[s] + lane;
            const int oc = (o < NW) ? o : (NW - 1);  // clamp for tail lanes (their keys are 0)
            const float4 cb = c_box[oc];             // ds_read_b128, coalesced
            const float ar = c_ar[oc];
            const float lxA = fminf(cb.z, bA.z) - fmaxf(cb.x, bA.x) + 1.0f;
            const float lyA = fminf(cb.w, bA.w) - fmaxf(cb.y, bA.y) + 1.0f;
            const float inA = (lxA < 0.0f || lyA < 0.0f) ? 0.0f : lxA * lyA;
            const bool supA = (4.0f * inA > ar + aA - inA);
            const float lxB = fminf(cb.z, bB.z) - fmaxf(cb.x, bB.x) + 1.0f;
            const float lyB = fminf(cb.w, bB.w) - fmaxf(cb.y, bB.y) + 1.0f;
            const float inB = (lxB < 0.0f || lyB < 0.0f) ? 0.0f : lxB * lyB;
            const bool supB = (4.0f * inB > ar + aB - inB);
            if (supA) kA[s] = 0u;   // register update, no LDS write-back
            if (supB) kB[s] = 0u;
          }
        }
      }
    }

    // ---- outputs ----
    if (lane < 6) {
      const long long a6 = (long long)imgA * 6 + lane;
      out[a6] = myIA;
      out[(long long)B * 6 + a6] = mySA;
      if (hasB) {
        const long long b6 = (long long)imgB * 6 + lane;
        out[b6] = myIB;
        out[(long long)B * 6 + b6] = mySB;
      }
    }
  }
}

extern "C" void kernel_launch(void* const* d_in, const int* in_sizes, int n_in,
                              void* d_out, int out_size, void* d_ws, size_t ws_size,
                              hipStream_t stream) {
  const float* x = (const float*)d_in[0];
  const int* coords = (const int*)d_in[1];
  float* out = (float*)d_out;
  const int B = in_sizes[0] / 196;
  const int nblk = (B + 7) / 8;
  appm_kernel<<<dim3(nblk), dim3(256), 0, stream>>>(x, coords, out, B);
}

// Round 2
// 380.182 us; speedup vs baseline: 1.1649x; 1.0508x over previous
//
#include <hip/hip_runtime.h>
#include <stdint.h>

#define NW 741
#define NEG_INF_KEY 0x007FFFFFu  // key(-inf); real finite scores map strictly above

typedef float f2 __attribute__((ext_vector_type(2)));

__device__ __forceinline__ unsigned score_key(float f) {
  const unsigned u = __float_as_uint(f);
  return (u & 0x80000000u) ? ~u : (u | 0x80000000u);
}
__device__ __forceinline__ float key_score(unsigned k) {
  return __uint_as_float((k & 0x80000000u) ? (k ^ 0x80000000u) : ~k);
}

// Wave argmax (tie -> lowest index) as max-reduce + readlane + masked
// min-index-reduce. ~28 VALU instrs vs ~40 for the compare-pair version.
// Per-lane scan already resolves within-lane ties to the lowest slot, so
// the cross-lane min over {lanes whose best key == smax} gives the global
// lowest index with the max key — identical semantics to the old reduction.
template<int CTRL>
__device__ __forceinline__ unsigned max_step(unsigned m) {
  const unsigned t = (unsigned)__builtin_amdgcn_update_dpp(0, (int)m, CTRL, 0xF, 0xF, true);
  return m > t ? m : t;   // v_max_u32 (fill=0 is harmless for max of unsigned keys)
}
template<int CTRL>
__device__ __forceinline__ int min_step(int c) {
  const int t = __builtin_amdgcn_update_dpp(0x7fffffff, c, CTRL, 0xF, 0xF, false);
  return c < t ? c : t;   // v_min_i32 (invalid lanes read INT_MAX)
}
__device__ __forceinline__ void wave_argmax(unsigned& k, int& i) {
  unsigned m = k;
  m = max_step<0x111>(m);  // row_shr:1
  m = max_step<0x112>(m);  // row_shr:2
  m = max_step<0x114>(m);  // row_shr:4
  m = max_step<0x118>(m);  // row_shr:8
  m = max_step<0x142>(m);  // row_bcast15
  m = max_step<0x143>(m);  // row_bcast31
  const unsigned smax = (unsigned)__builtin_amdgcn_readlane((int)m, 63);
  int ci = (k == smax) ? i : 0x7fffffff;
  ci = min_step<0x111>(ci);
  ci = min_step<0x112>(ci);
  ci = min_step<0x114>(ci);
  ci = min_step<0x118>(ci);
  ci = min_step<0x142>(ci);
  ci = min_step<0x143>(ci);
  k = smax;
  i = __builtin_amdgcn_readlane(ci, 63);
}

// Bit-exact chained row-major fp32 window sum for TWO images at once.
// im2[k] = {imgA[k], imgB[k]}; per-component adds are independent IEEE fp32
// chains identical to the reference order (v_pk_add_f32), then IEEE div.
// Keys go to REGISTER slots kA/kB[SB..SB+NS) (no LDS).
// Single image copy: R1 measured that dense b64 reads carry ~3 intrinsic
// "conflict" cycles regardless of layout (4 dword-addrs/bank), so copy
// rotation bought nothing — spend the LDS on occupancy instead.
template<int H, int W, int OFF, int NS, int SB>
__device__ __forceinline__ void score_ratio2(const f2* __restrict__ im2,
                                             unsigned* __restrict__ kA,
                                             unsigned* __restrict__ kB,
                                             float* __restrict__ wrowA,
                                             float* __restrict__ wrowB,
                                             const int lane, const bool hasB) {
  constexpr int Wo = 14 - W + 1;
  constexpr int Ho = 14 - H + 1;
  constexpr int NWIN = Ho * Wo;
#pragma unroll
  for (int s = 0; s < NS; ++s) {
    const int o = lane + 64 * s;
    unsigned ka = 0u, kb = 0u;
    if (o < NWIN) {
      const int i = o / Wo, j = o - i * Wo;
      const f2* p = im2 + (i * 14 + j);
      f2 acc = {0.0f, 0.0f};
#pragma unroll
      for (int di = 0; di < H; ++di)
#pragma unroll
        for (int dj = 0; dj < W; ++dj)
          acc += p[di * 14 + dj];           // ds_read_b64, chained adds
      const float scA = acc.x / (float)(H * W);   // IEEE fp32 div (bit-exact)
      const float scB = acc.y / (float)(H * W);
      wrowA[OFF + o] = scA;
      if (hasB) wrowB[OFF + o] = scB;
      ka = score_key(scA);
      kb = score_key(scB);
    }
    kA[SB + s] = ka;   // constant index after unroll -> stays in VGPRs
    kB[SB + s] = kb;
  }
}

__global__ __launch_bounds__(256, 8) void appm_kernel(
    const float* __restrict__ x, const int* __restrict__ coords,
    float* __restrict__ out, int B) {

  __shared__ float4 c_box[NW];      // 11856 B
  __shared__ f2 imgp[4][196];       // 6272 B: per wave, 196 x {imgA, imgB}
  // LDS total 18128 B -> 8 blocks/CU (2048 threads, 100% nominal occupancy)

  const int t = threadIdx.x;
  const int wv = t >> 6;
  const int lane = t & 63;
  const int img0 = blockIdx.x * 8;
  const int imgA = img0 + wv * 2;
  const int imgB = imgA + 1;
  const bool hasA = (imgA < B);
  const bool hasB = (imgB < B);

  // ---- Phase A: coord table (float4 box), shared per block ----
  for (int w = t; w < NW; w += 256) {
    const int4 c = ((const int4*)coords)[w];
    c_box[w] = make_float4((float)c.x, (float)c.y, (float)c.z, (float)c.w);
  }

  // ---- Phase B: stage 8 images as 4 pair-interleaved f2 planes ----
  {
    int nimg = B - img0; if (nimg > 8) nimg = 8;
    const float* xb = x + (long long)img0 * 196;
    for (int u = t; u < 784; u += 256) {        // 784 = 4 pairs * 196
      const int pr = u / 196, k = u - pr * 196;
      const int iA = 2 * pr, iB = iA + 1;
      f2 v;
      v.x = (iA < nimg) ? xb[iA * 196 + k] : 0.0f;
      v.y = (iB < nimg) ? xb[iB * 196 + k] : 0.0f;
      imgp[pr][k] = v;                          // ds_write_b64, dense
    }
  }
  __syncthreads();

  if (hasA) {
    const f2* im2 = imgp[wv];
    float* wrowA = out + (long long)B * 12 + (long long)imgA * NW;
    float* wrowB = wrowA + NW;

    // Register key slots: {ratio,slot} -> global slot id. 15 per image.
    unsigned kA[15], kB[15];

    // ---- Phase C: 741 window scores for both images ----
    score_ratio2<4, 4, 0, 2, 0>(im2, kA, kB, wrowA, wrowB, lane, hasB);
    score_ratio2<3, 5, 121, 2, 2>(im2, kA, kB, wrowA, wrowB, lane, hasB);
    score_ratio2<5, 3, 241, 2, 4>(im2, kA, kB, wrowA, wrowB, lane, hasB);
    score_ratio2<6, 6, 361, 2, 6>(im2, kA, kB, wrowA, wrowB, lane, hasB);
    score_ratio2<5, 7, 442, 2, 8>(im2, kA, kB, wrowA, wrowB, lane, hasB);
    score_ratio2<7, 5, 522, 2, 10>(im2, kA, kB, wrowA, wrowB, lane, hasB);
    score_ratio2<8, 8, 602, 1, 12>(im2, kA, kB, wrowA, wrowB, lane, hasB);
    score_ratio2<6, 10, 651, 1, 13>(im2, kA, kB, wrowA, wrowB, lane, hasB);
    score_ratio2<10, 6, 696, 1, 14>(im2, kA, kB, wrowA, wrowB, lane, hasB);

    // ---- Phase D: greedy NMS for both images, 3 groups, keys in VGPRs ----
    constexpr int SBASE[15] = {0, 64, 121, 185, 241, 305, 361, 425,
                               442, 506, 522, 586, 602, 651, 696};
    constexpr int GS[3] = {0, 6, 12};
    constexpr int GE[3] = {6, 12, 15};
    constexpr int GN[3] = {3, 2, 1};
    constexpr int GW0[3] = {0, 361, 602};   // group start window index

    float myIA = 0.0f, mySA = 0.0f, myIB = 0.0f, mySB = 0.0f;
    int pick = 0;
#pragma unroll
    for (int g = 0; g < 3; ++g) {
      int lastA = GW0[g], lastB = GW0[g];
      float lastSA = 0.0f, lastSB = 0.0f;
#pragma unroll
      for (int n = 0; n < GN[g]; ++n) {
        unsigned bkA = 0u, bkB = 0u;
        int biA = 0, biB = 0;
#pragma unroll
        for (int s = GS[g]; s < GE[g]; ++s) {   // register scan (no LDS)
          const int o = SBASE[s] + lane;
          if (kA[s] > bkA) { bkA = kA[s]; biA = o; }
          if (kB[s] > bkB) { bkB = kB[s]; biB = o; }
        }
        wave_argmax(bkA, biA);
        wave_argmax(bkB, biB);

        int idxA, idxB; float scA, scB;
        if (bkA > NEG_INF_KEY) { idxA = biA; scA = key_score(bkA); }
        else { idxA = lastA; scA = lastSA; }
        if (bkB > NEG_INF_KEY) { idxB = biB; scB = key_score(bkB); }
        else { idxB = lastB; scB = lastSB; }
        lastA = idxA; lastSA = scA;
        lastB = idxB; lastSB = scB;
        if (lane == pick) { myIA = (float)idxA; mySA = scA; myIB = (float)idxB; mySB = scB; }
        pick++;

        if (n + 1 < GN[g]) {
          // suppression: exact compare 4*inter > union  <=>  iou > 0.25
          // (all quantities are integers < 2^24 -> fp32-exact)
          const float4 bA = c_box[idxA];   // broadcast read
          const float4 bB = c_box[idxB];
          const float aA = (bA.z - bA.x + 1.0f) * (bA.w - bA.y + 1.0f);
          const float aB = (bB.z - bB.x + 1.0f) * (bB.w - bB.y + 1.0f);
#pragma unroll
          for (int s = GS[g]; s < GE[g]; ++s) {
            const int o = SBASE[s] + lane;
            const int oc = (o < NW) ? o : (NW - 1);  // clamp tail lanes (keys are 0)
            const float4 cb = c_box[oc];             // ds_read_b128, coalesced
            const float ar = (cb.z - cb.x + 1.0f) * (cb.w - cb.y + 1.0f);
            const float lxA = fminf(cb.z, bA.z) - fmaxf(cb.x, bA.x) + 1.0f;
            const float lyA = fminf(cb.w, bA.w) - fmaxf(cb.y, bA.y) + 1.0f;
            const float inA = (lxA < 0.0f || lyA < 0.0f) ? 0.0f : lxA * lyA;
            const bool supA = (4.0f * inA > ar + aA - inA);
            const float lxB = fminf(cb.z, bB.z) - fmaxf(cb.x, bB.x) + 1.0f;
            const float lyB = fminf(cb.w, bB.w) - fmaxf(cb.y, bB.y) + 1.0f;
            const float inB = (lxB < 0.0f || lyB < 0.0f) ? 0.0f : lxB * lyB;
            const bool supB = (4.0f * inB > ar + aB - inB);
            if (supA) kA[s] = 0u;   // register update, no LDS write-back
            if (supB) kB[s] = 0u;
          }
        }
      }
    }

    // ---- outputs ----
    if (lane < 6) {
      const long long a6 = (long long)imgA * 6 + lane;
      out[a6] = myIA;
      out[(long long)B * 6 + a6] = mySA;
      if (hasB) {
        const long long b6 = (long long)imgB * 6 + lane;
        out[b6] = myIB;
        out[(long long)B * 6 + b6] = mySB;
      }
    }
  }
}

extern "C" void kernel_launch(void* const* d_in, const int* in_sizes, int n_in,
                              void* d_out, int out_size, void* d_ws, size_t ws_size,
                              hipStream_t stream) {
  const float* x = (const float*)d_in[0];
  const int* coords = (const int*)d_in[1];
  float* out = (float*)d_out;
  const int B = in_sizes[0] / 196;
  const int nblk = (B + 7) / 8;
  appm_kernel<<<dim3(nblk), dim3(256), 0, stream>>>(x, coords, out, B);
}